// Round 8
// baseline (814.808 us; speedup 1.0000x reference)
//
#include <hip/hip_runtime.h>
#include <stdint.h>

// MultiHeadAttention: B=2, S=2048, D=1024, H=16, Dh=64. fp32 in/out, bf16 MFMA inside.
// R15: attn occupancy round (GEMMs unchanged).
//  R14 null (compiler had already pipelined; VGPR unchanged) -> revised theory:
//  latency-bound at 4 waves/SIMD, occupancy capped by LDS/grid (2 blocks/CU).
//  Fix: QBLK 128->64 (Qs 16->8KB, block LDS 40KB) -> grid 1024 = 4 blocks/CU =
//  32 waves/CU (8/SIMD). Waves = 2 q-tiles(32r) x 4 kv-quarters(32kv): per-wave
//  work halves, wave count doubles -> same total LDS/MFMA/exp. Two-stage O/l
//  merge cascade (4->2->1) through reused LDS. __launch_bounds__(512,8) pins
//  VGPR<=64 (R13/R14 compiled at exactly 64 with same live state).
// Carried: Q pre-scale in GEMM epilogue, raw v_exp_f32, v_perm P-pack, fused
// V-transpose, 64x64 O-GEMM.

typedef unsigned short u16;
typedef short s16x8 __attribute__((ext_vector_type(8)));   // 8 bf16 (4 VGPR)
typedef short s16x4 __attribute__((ext_vector_type(4)));   // 4 bf16 (2 VGPR)
typedef float f32x4 __attribute__((ext_vector_type(4)));
typedef u16 u16x4 __attribute__((ext_vector_type(4)));

#define S_LEN 2048
#define DMODEL 1024
#define LOG2E 1.44269504088896340736f

__device__ __forceinline__ u16 f2bf(float f) {
  union { float f; uint32_t u; } v; v.f = f;
  return (u16)((v.u + 0x8000u) >> 16);
}

__device__ __forceinline__ s16x8 ld8f(const float* s) {  // 8 fp32 -> 8 bf16
  f32x4 a = *(const f32x4*)s;
  f32x4 b = *(const f32x4*)(s + 4);
  s16x8 r;
  r[0] = (short)f2bf(a[0]); r[1] = (short)f2bf(a[1]);
  r[2] = (short)f2bf(a[2]); r[3] = (short)f2bf(a[3]);
  r[4] = (short)f2bf(b[0]); r[5] = (short)f2bf(b[1]);
  r[6] = (short)f2bf(b[2]); r[7] = (short)f2bf(b[3]);
  return r;
}

// async global->LDS, 16B/lane; HW scatters lane i to ldsbase + i*16
__device__ __forceinline__ void gl2lds16(const u16* g, u16* l) {
  __builtin_amdgcn_global_load_lds(
      (const __attribute__((address_space(1))) uint32_t*)g,
      (__attribute__((address_space(3))) uint32_t*)l, 16, 0, 0);
}

// ---------------------------------------------------------------------------
// fp32 -> bf16 conversion: 4 weights (1M elem) + 3 activations (4.19M elem).
// ---------------------------------------------------------------------------
struct Cvt7 { const float* s[7]; u16* d[7]; int n[7]; };

__global__ __launch_bounds__(256) void cvt7(Cvt7 p) {
  const int z = blockIdx.y;
  const int idx = blockIdx.x * 256 + threadIdx.x;
  if (idx * 8 < p.n[z])
    *(s16x8*)(p.d[z] + (size_t)idx * 8) = ld8f(p.s[z] + (size_t)idx * 8);
}

// ---------------------------------------------------------------------------
// GEMM: C[M,N] = (A[M,K] @ W[N,K]^T + bias[N]) * scl; A,W bf16, bias fp32.
// scl=1.0 for all but the Q projection (score scale folded in, fp32 pre-round).
// Template: BM x BN tile (BK=64 fixed), 4 waves as 2x2 of (BM/2 x BN/2).
// OUT_F32: fp32 C (O projection). VT: z==2 writes transposed bf16 to p.vt.
// ---------------------------------------------------------------------------
struct GemmBatch {
  const u16* A[3]; const u16* W[3]; const float* Bv[3]; void* C[3];
  u16* vt;       // VT destination: Vt[(b*16+h)*64+dh][s], row stride S_LEN
  float scl[3];  // epilogue scale (fp32, applied before f2bf round)
};

template <int BM, int BN, bool OUT_F32, bool VT>
__global__ __launch_bounds__(256) void gemm_bt(GemmBatch p, int M, int N, int K) {
  static_assert(!VT || (BM == 128 && BN == 128), "VT epilogue assumes 128x128");
  constexpr int MI = BM / 32, NJ = BN / 32;   // fragment repeats per wave
  constexpr int TS = BM + 8;                  // VT transpose stride (u16), 16B-aligned
  constexpr int AB = BM * 64 + BN * 64;
  constexpr int TB = VT ? BN * TS : 0;
  constexpr int SM = AB > TB ? AB : TB;
  __shared__ u16 smem[SM];
  u16* const As = smem;
  u16* const Ws = smem + BM * 64;

  const int z = blockIdx.z;
  const u16* __restrict__ A      = p.A[z];
  const u16* __restrict__ W      = p.W[z];
  const float* __restrict__ bias = p.Bv[z];
  const float scl = p.scl[z];

  const int tid = threadIdx.x;
  const int wave = tid >> 6, lane = tid & 63;
  const int quad = lane >> 4, l16 = lane & 15;
  const int bm = blockIdx.y * BM, bn = blockIdx.x * BN;
  const int wr = (wave >> 1) * (BM / 2), wc = (wave & 1) * (BN / 2);
  const int sr8 = lane >> 3;
  const int slc = (lane & 7) ^ sr8;           // logical k-chunk to fetch
  const int srow = wave * 8 + sr8;            // row within 32-row stripe

  f32x4 acc[MI][NJ];
#pragma unroll
  for (int i = 0; i < MI; i++)
#pragma unroll
    for (int j = 0; j < NJ; j++) acc[i][j] = {0.f, 0.f, 0.f, 0.f};

  const u16* Ab = A + (size_t)bm * K;
  const u16* Wb = W + (size_t)bn * K;

  for (int kt = 0; kt < K; kt += 64) {
    __syncthreads();  // previous iteration's LDS reads complete
#pragma unroll
    for (int i = 0; i < MI; i++)
      gl2lds16(Ab + (size_t)(i * 32 + srow) * K + kt + slc * 8,
               &As[(i * 32 + wave * 8) * 64]);
#pragma unroll
    for (int i = 0; i < NJ; i++)
      gl2lds16(Wb + (size_t)(i * 32 + srow) * K + kt + slc * 8,
               &Ws[(i * 32 + wave * 8) * 64]);
    __syncthreads();  // drains vmcnt (async loads) + LDS visible

#pragma unroll
    for (int ks = 0; ks < 2; ks++) {
      const int ch = ks * 4 + quad;  // logical chunk of this fragment
      s16x8 a[MI], b[NJ];
#pragma unroll
      for (int t = 0; t < MI; t++)
        a[t] = *(const s16x8*)&As[(wr + t * 16 + l16) * 64 + ((ch ^ (l16 & 7)) << 3)];
#pragma unroll
      for (int t = 0; t < NJ; t++)
        b[t] = *(const s16x8*)&Ws[(wc + t * 16 + l16) * 64 + ((ch ^ (l16 & 7)) << 3)];
#pragma unroll
      for (int i = 0; i < MI; i++)
#pragma unroll
        for (int j = 0; j < NJ; j++)
          acc[i][j] = __builtin_amdgcn_mfma_f32_16x16x32_bf16(a[i], b[j], acc[i][j], 0, 0, 0);
    }
  }

  if (VT && z == 2) {
    // ---- fused V transpose: acc -> LDS [col][row] -> Vt[d-row][s] ----
    __syncthreads();               // all waves done reading As/Ws
    u16* const T = smem;           // [BN][TS]
#pragma unroll
    for (int j = 0; j < NJ; j++) {
      const int c = wc + j * 16 + l16;
      const float bv = bias[bn + c];
#pragma unroll
      for (int i = 0; i < MI; i++) {
        const int r0 = wr + i * 16 + quad * 4;
        u16x4 t4;
#pragma unroll
        for (int r = 0; r < 4; r++) t4[r] = f2bf((acc[i][j][r] + bv) * scl);
        *(u16x4*)&T[c * TS + r0] = t4;
      }
    }
    __syncthreads();
    // thread -> (c = tid>>1, half = tid&1): 64 contiguous s per thread
    const int c = tid >> 1, half = tid & 1;
    const int b_ = bm >> 11;                 // batch (2048 rows each, 128 | 2048)
    const int sb = (bm & 2047) + half * 64;  // s within batch
    u16* dst = p.vt + (size_t)(b_ * 1024 + bn + c) * S_LEN + sb;
    const u16* srcT = &T[c * TS + half * 64];
#pragma unroll
    for (int k = 0; k < 8; k++)
      *(s16x8*)(dst + k * 8) = *(const s16x8*)(srcT + k * 8);
  } else {
    // epilogue: C/D layout row = quad*4 + reg, col = lane&15
#pragma unroll
    for (int j = 0; j < NJ; j++) {
      const int col = bn + wc + j * 16 + l16;
      const float bv = bias[col];
#pragma unroll
      for (int i = 0; i < MI; i++) {
        const int row0 = bm + wr + i * 16 + quad * 4;
#pragma unroll
        for (int r = 0; r < 4; r++) {
          const float val = (acc[i][j][r] + bv) * scl;
          if (OUT_F32)
            ((float*)p.C[z])[(size_t)(row0 + r) * N + col] = val;
          else
            ((u16*)p.C[z])[(size_t)(row0 + r) * N + col] = f2bf(val);
        }
      }
    }
  }
}

// ---------------------------------------------------------------------------
// Flash attention R15: QBLK=64, 512 threads = 8 waves = 2 q-tiles(32 rows) x
// 4 kv-quarters(32 kv). LDS 40KB -> 4 blocks/CU = 32 waves/CU (8/SIMD).
// Grid (32,32) = 1024 blocks. Two-stage end merge: waves 4-7 dump O/l, waves
// 0-3 add; waves 2-3 dump; waves 0-1 add + normalize + store.
// ---------------------------------------------------------------------------
__global__ __launch_bounds__(512, 8) void attn_kernel(const u16* __restrict__ Qp,
                                                      const u16* __restrict__ Kp,
                                                      const u16* __restrict__ Vt,
                                                      u16* __restrict__ AO) {
  __shared__ u16 smem[20480];    // 40 KB
  u16* const Qs = smem;          // [q:64][d:64]    8 KB, 8-chunk XOR swizzle
  u16* const Ks = smem + 4096;   // [kv:128][d:64] 16 KB, 8-chunk XOR swizzle
  u16* const Vs = smem + 12288;  // [d:64][kv:128] 16 KB, 16-chunk XOR swizzle

  const int tid = threadIdx.x;
  const int wave = tid >> 6, lane = tid & 63;
  const int quad = lane >> 4, l16 = lane & 15;
  const int bh = blockIdx.y, b = bh >> 4, h = bh & 15;
  const int s0 = blockIdx.x * 64;
  const int qw = wave & 1;        // q-tile index (32 rows each)
  const int kvq = wave >> 1;      // kv quarter (32 kv rows each)

  const int sr = tid >> 3, sc8 = tid & 7;     // sr in [0,64)
  const int sxor = (sc8 ^ (sr & 7)) << 3;
  const int vr = tid >> 4, vc = tid & 15;     // vr in [0,32)
  const int vxor = (vc ^ (vr & 15)) << 3;

  // ---- Q stage (64 rows, one shot) + per-wave fragments (32 rows) ----
  {
    s16x8 qv = *(const s16x8*)(Qp + (size_t)(b * S_LEN + s0 + sr) * DMODEL + h * 64 + sc8 * 8);
    *(s16x8*)&Qs[sr * 64 + sxor] = qv;
  }
  __syncthreads();

  s16x8 aq[2][2];  // [ks][rt]
#pragma unroll
  for (int ks = 0; ks < 2; ks++)
#pragma unroll
    for (int rt = 0; rt < 2; rt++) {
      const int row = qw * 32 + rt * 16 + l16;
      const int ch = ks * 4 + quad;
      aq[ks][rt] = *(const s16x8*)&Qs[row * 64 + ((ch ^ (l16 & 7)) << 3)];
    }

  // ---- K/V register prefetch for kt=0 (cooperative staging) ----
  s16x8 kv[2], vv[2];
#pragma unroll
  for (int i = 0; i < 2; i++)
    kv[i] = *(const s16x8*)(Kp + (size_t)(b * S_LEN + i * 64 + sr) * DMODEL + h * 64 + sc8 * 8);
#pragma unroll
  for (int i = 0; i < 2; i++)
    vv[i] = *(const s16x8*)(Vt + (size_t)(bh * 64 + i * 32 + vr) * S_LEN + vc * 8);

  f32x4 o[2][4];
  float l_r[2] = {0.f, 0.f};
#pragma unroll
  for (int rt = 0; rt < 2; rt++)
#pragma unroll
    for (int dt = 0; dt < 4; dt++) o[rt][dt] = {0.f, 0.f, 0.f, 0.f};

  const f32x4 zf = {0.f, 0.f, 0.f, 0.f};

  for (int kt = 0; kt < S_LEN; kt += 128) {
    __syncthreads();
#pragma unroll
    for (int i = 0; i < 2; i++)
      *(s16x8*)&Ks[(i * 64 + sr) * 64 + sxor] = kv[i];
#pragma unroll
    for (int i = 0; i < 2; i++)
      *(s16x8*)&Vs[(i * 32 + vr) * 128 + vxor] = vv[i];
    __syncthreads();

    if (kt + 128 < S_LEN) {
      const int k2 = kt + 128;
#pragma unroll
      for (int i = 0; i < 2; i++)
        kv[i] = *(const s16x8*)(Kp + (size_t)(b * S_LEN + k2 + i * 64 + sr) * DMODEL + h * 64 + sc8 * 8);
#pragma unroll
      for (int i = 0; i < 2; i++)
        vv[i] = *(const s16x8*)(Vt + (size_t)(bh * 64 + i * 32 + vr) * S_LEN + k2 + vc * 8);
    }

    // ---- this wave's kv quarter: rows kvq*32 .. kvq*32+31 (2 subtiles) ----
#pragma unroll
    for (int kvt = 0; kvt < 2; kvt++) {
      const int krow = kvq * 32 + kvt * 16 + l16;   // krow&7 == l16&7
      s16x8 ak0 = *(const s16x8*)&Ks[krow * 64 + (((0 + quad) ^ (l16 & 7)) << 3)];
      s16x8 ak1 = *(const s16x8*)&Ks[krow * 64 + (((4 + quad) ^ (l16 & 7)) << 3)];

      s16x4 pf[2];
#pragma unroll
      for (int rt = 0; rt < 2; rt++) {
        f32x4 sA;
        sA = __builtin_amdgcn_mfma_f32_16x16x32_bf16(ak0, aq[0][rt], zf, 0, 0, 0);
        sA = __builtin_amdgcn_mfma_f32_16x16x32_bf16(ak1, aq[1][rt], sA, 0, 0, 0);

        union { float f; uint32_t u; } e0, e1, e2, e3;
        e0.f = __builtin_amdgcn_exp2f(sA[0]);
        e1.f = __builtin_amdgcn_exp2f(sA[1]);
        e2.f = __builtin_amdgcn_exp2f(sA[2]);
        e3.f = __builtin_amdgcn_exp2f(sA[3]);
        l_r[rt] += (((e0.f + e1.f) + e2.f) + e3.f);

        union { uint32_t u[2]; s16x4 v; } pk;
        pk.u[0] = __builtin_amdgcn_perm(e1.u + 0x8000u, e0.u + 0x8000u, 0x07060302u);
        pk.u[1] = __builtin_amdgcn_perm(e3.u + 0x8000u, e2.u + 0x8000u, 0x07060302u);
        pf[rt] = pk.v;
      }

      const int ch = kvq * 4 + kvt * 2 + (quad >> 1);
#pragma unroll
      for (int dt = 0; dt < 4; dt++) {
        const int row = dt * 16 + l16;
        s16x4 bv = *(const s16x4*)&Vs[row * 128 + ((ch ^ l16) << 3) + (quad & 1) * 4];
        o[0][dt] = __builtin_amdgcn_mfma_f32_16x16x16bf16_1k(pf[0], bv, o[0][dt], 0, 0, 0);
        o[1][dt] = __builtin_amdgcn_mfma_f32_16x16x16bf16_1k(pf[1], bv, o[1][dt], 0, 0, 0);
      }
    }
  }

  // intra-wave l reduction (sum over quads -> value depends on l16 only)
#pragma unroll
  for (int rt = 0; rt < 2; rt++) {
    l_r[rt] += __shfl_xor(l_r[rt], 16);
    l_r[rt] += __shfl_xor(l_r[rt], 32);
  }

  // ---- two-stage cross-quarter merge through reused LDS ----
  // layout: mrgO[slot:4][rt*4+dt:8][lane:64] f32x4 (32 KB), mrgL[slot:4][rt:2][lane] (2 KB)
  f32x4* const mrgO = (f32x4*)smem;
  float* const mrgL = (float*)(smem + 16384);  // 32 KB offset (u16 idx 16384)
  __syncthreads();  // all LDS reads of last ktile complete
  if (wave >= 4) {   // kvq 2,3 -> slots 0..3
    const int slot = wave - 4;
#pragma unroll
    for (int rt = 0; rt < 2; rt++) {
#pragma unroll
      for (int dt = 0; dt < 4; dt++)
        mrgO[(slot * 8 + rt * 4 + dt) * 64 + lane] = o[rt][dt];
      mrgL[(slot * 2 + rt) * 64 + lane] = l_r[rt];
    }
  }
  __syncthreads();
  if (wave < 4) {    // merge partner wave+4 (same qw, kvq+2)
    const int slot = wave;
#pragma unroll
    for (int rt = 0; rt < 2; rt++) {
#pragma unroll
      for (int dt = 0; dt < 4; dt++)
        o[rt][dt] += mrgO[(slot * 8 + rt * 4 + dt) * 64 + lane];
      l_r[rt] += mrgL[(slot * 2 + rt) * 64 + lane];
    }
  }
  __syncthreads();
  if (wave >= 2 && wave < 4) {  // kvq==1 -> slots 0,1
    const int slot = wave - 2;
#pragma unroll
    for (int rt = 0; rt < 2; rt++) {
#pragma unroll
      for (int dt = 0; dt < 4; dt++)
        mrgO[(slot * 8 + rt * 4 + dt) * 64 + lane] = o[rt][dt];
      mrgL[(slot * 2 + rt) * 64 + lane] = l_r[rt];
    }
  }
  __syncthreads();
  if (wave < 2) {    // final: merge wave+2, normalize, store (qw == wave)
    const int slot = wave;
#pragma unroll
    for (int rt = 0; rt < 2; rt++) {
#pragma unroll
      for (int dt = 0; dt < 4; dt++)
        o[rt][dt] += mrgO[(slot * 8 + rt * 4 + dt) * 64 + lane];
      l_r[rt] += mrgL[(slot * 2 + rt) * 64 + lane];
    }
#pragma unroll
    for (int rt = 0; rt < 2; rt++) {
#pragma unroll
      for (int r = 0; r < 4; r++) {
        const float linv = 1.f / __shfl(l_r[rt], quad * 4 + r);
        const int row = s0 + wave * 32 + rt * 16 + quad * 4 + r;
#pragma unroll
        for (int dt = 0; dt < 4; dt++)
          AO[(size_t)(b * S_LEN + row) * DMODEL + h * 64 + dt * 16 + l16] =
              f2bf(o[rt][dt][r] * linv);
      }
    }
  }
}

// ---------------------------------------------------------------------------
extern "C" void kernel_launch(void* const* d_in, const int* in_sizes, int n_in,
                              void* d_out, int out_size, void* d_ws, size_t ws_size,
                              hipStream_t stream) {
  const float* query = (const float*)d_in[0];
  const float* key_  = (const float*)d_in[1];
  const float* value = (const float*)d_in[2];
  const float* W_q = (const float*)d_in[3];
  const float* b_q = (const float*)d_in[4];
  const float* W_k = (const float*)d_in[5];
  const float* b_k = (const float*)d_in[6];
  const float* W_v = (const float*)d_in[7];
  const float* b_v = (const float*)d_in[8];
  const float* W_o = (const float*)d_in[9];
  const float* b_o = (const float*)d_in[10];
  float* out = (float*)d_out;

  const int M = 2 * S_LEN;  // 4096
  const int N = DMODEL, K = DMODEL;
  const size_t WSZ = (size_t)DMODEL * DMODEL;   // 1,048,576
  const size_t SZ  = (size_t)M * DMODEL;        // 4,194,304

  u16* Wqb = (u16*)d_ws;         // 4 bf16 weights
  u16* Wkb = Wqb + WSZ;
  u16* Wvb = Wkb + WSZ;
  u16* Wob = Wvb + WSZ;
  u16* Qa  = Wob + WSZ;          // bf16 inputs (dead after QKV GEMM)
  u16* Ka  = Qa + SZ;
  u16* Va  = Ka + SZ;
  u16* Qp  = Va + SZ;            // projections
  u16* Kp  = Qp + SZ;
  u16* Vt  = Kp + SZ;            // [B,H,Dh,S] -- written directly by V-GEMM (VT path)
  u16* AO  = Qp;                 // aliases Qp (per-block disjoint read->write)

  Cvt7 cw;
  cw.s[0] = W_q;   cw.d[0] = Wqb; cw.n[0] = (int)WSZ;
  cw.s[1] = W_k;   cw.d[1] = Wkb; cw.n[1] = (int)WSZ;
  cw.s[2] = W_v;   cw.d[2] = Wvb; cw.n[2] = (int)WSZ;
  cw.s[3] = W_o;   cw.d[3] = Wob; cw.n[3] = (int)WSZ;
  cw.s[4] = query; cw.d[4] = Qa;  cw.n[4] = (int)SZ;
  cw.s[5] = key_;  cw.d[5] = Ka;  cw.n[5] = (int)SZ;
  cw.s[6] = value; cw.d[6] = Va;  cw.n[6] = (int)SZ;
  cvt7<<<dim3((int)(SZ / 2048), 7), 256, 0, stream>>>(cw);

  GemmBatch p1;
  p1.A[0] = Qa; p1.W[0] = Wqb; p1.Bv[0] = b_q; p1.C[0] = Qp;
  p1.A[1] = Ka; p1.W[1] = Wkb; p1.Bv[1] = b_k; p1.C[1] = Kp;
  p1.A[2] = Va; p1.W[2] = Wvb; p1.Bv[2] = b_v; p1.C[2] = Vt;  // unused (VT path)
  p1.vt = Vt;
  p1.scl[0] = 0.03125f * LOG2E;  // d_model^-0.5 * log2(e) folded into Q (fp32)
  p1.scl[1] = 1.0f;
  p1.scl[2] = 1.0f;
  gemm_bt<128, 128, false, true><<<dim3(N / 128, M / 128, 3), 256, 0, stream>>>(p1, M, N, K);

  attn_kernel<<<dim3(S_LEN / 64, 32), 512, 0, stream>>>(Qp, Kp, Vt, AO);

  GemmBatch p2;
  p2.A[0] = AO; p2.W[0] = Wob; p2.Bv[0] = b_o; p2.C[0] = out;
  p2.A[1] = AO; p2.W[1] = Wob; p2.Bv[1] = b_o; p2.C[1] = out;
  p2.A[2] = AO; p2.W[2] = Wob; p2.Bv[2] = b_o; p2.C[2] = out;
  p2.vt = nullptr;
  p2.scl[0] = 1.0f; p2.scl[1] = 1.0f; p2.scl[2] = 1.0f;
  gemm_bt<64, 64, true, false><<<dim3(N / 64, M / 64, 1), 256, 0, stream>>>(p2, M, N, K);
}

// Round 9
// 229.119 us; speedup vs baseline: 3.5563x; 3.5563x over previous
//
#include <hip/hip_runtime.h>
#include <stdint.h>

// MultiHeadAttention: B=2, S=2048, D=1024, H=16, Dh=64. fp32 in/out, bf16 MFMA inside.
// R16: R15 with the launch-bound bug fixed. R15's 635us regression was entirely
// __launch_bounds__(512,8) forcing a 32-VGPR cap (live state ~64) -> full spill,
// FETCH 1.18GB of scratch. (512,4) caps at 128; R13/14 identical live state
// compiled to 64 unforced -> expect 64-80, no spill, 3-4 blocks/CU (6-8 w/SIMD).
// Structure (QBLK=64, 2 q-tiles x 4 kv-quarters, two-stage merge) unchanged.
// Carried: Q pre-scale in GEMM epilogue, raw v_exp_f32, v_perm P-pack, fused
// V-transpose, 64x64 O-GEMM.

typedef unsigned short u16;
typedef short s16x8 __attribute__((ext_vector_type(8)));   // 8 bf16 (4 VGPR)
typedef short s16x4 __attribute__((ext_vector_type(4)));   // 4 bf16 (2 VGPR)
typedef float f32x4 __attribute__((ext_vector_type(4)));
typedef u16 u16x4 __attribute__((ext_vector_type(4)));

#define S_LEN 2048
#define DMODEL 1024
#define LOG2E 1.44269504088896340736f

__device__ __forceinline__ u16 f2bf(float f) {
  union { float f; uint32_t u; } v; v.f = f;
  return (u16)((v.u + 0x8000u) >> 16);
}

__device__ __forceinline__ s16x8 ld8f(const float* s) {  // 8 fp32 -> 8 bf16
  f32x4 a = *(const f32x4*)s;
  f32x4 b = *(const f32x4*)(s + 4);
  s16x8 r;
  r[0] = (short)f2bf(a[0]); r[1] = (short)f2bf(a[1]);
  r[2] = (short)f2bf(a[2]); r[3] = (short)f2bf(a[3]);
  r[4] = (short)f2bf(b[0]); r[5] = (short)f2bf(b[1]);
  r[6] = (short)f2bf(b[2]); r[7] = (short)f2bf(b[3]);
  return r;
}

// async global->LDS, 16B/lane; HW scatters lane i to ldsbase + i*16
__device__ __forceinline__ void gl2lds16(const u16* g, u16* l) {
  __builtin_amdgcn_global_load_lds(
      (const __attribute__((address_space(1))) uint32_t*)g,
      (__attribute__((address_space(3))) uint32_t*)l, 16, 0, 0);
}

// ---------------------------------------------------------------------------
// fp32 -> bf16 conversion: 4 weights (1M elem) + 3 activations (4.19M elem).
// ---------------------------------------------------------------------------
struct Cvt7 { const float* s[7]; u16* d[7]; int n[7]; };

__global__ __launch_bounds__(256) void cvt7(Cvt7 p) {
  const int z = blockIdx.y;
  const int idx = blockIdx.x * 256 + threadIdx.x;
  if (idx * 8 < p.n[z])
    *(s16x8*)(p.d[z] + (size_t)idx * 8) = ld8f(p.s[z] + (size_t)idx * 8);
}

// ---------------------------------------------------------------------------
// GEMM: C[M,N] = (A[M,K] @ W[N,K]^T + bias[N]) * scl; A,W bf16, bias fp32.
// scl=1.0 for all but the Q projection (score scale folded in, fp32 pre-round).
// Template: BM x BN tile (BK=64 fixed), 4 waves as 2x2 of (BM/2 x BN/2).
// OUT_F32: fp32 C (O projection). VT: z==2 writes transposed bf16 to p.vt.
// ---------------------------------------------------------------------------
struct GemmBatch {
  const u16* A[3]; const u16* W[3]; const float* Bv[3]; void* C[3];
  u16* vt;       // VT destination: Vt[(b*16+h)*64+dh][s], row stride S_LEN
  float scl[3];  // epilogue scale (fp32, applied before f2bf round)
};

template <int BM, int BN, bool OUT_F32, bool VT>
__global__ __launch_bounds__(256) void gemm_bt(GemmBatch p, int M, int N, int K) {
  static_assert(!VT || (BM == 128 && BN == 128), "VT epilogue assumes 128x128");
  constexpr int MI = BM / 32, NJ = BN / 32;   // fragment repeats per wave
  constexpr int TS = BM + 8;                  // VT transpose stride (u16), 16B-aligned
  constexpr int AB = BM * 64 + BN * 64;
  constexpr int TB = VT ? BN * TS : 0;
  constexpr int SM = AB > TB ? AB : TB;
  __shared__ u16 smem[SM];
  u16* const As = smem;
  u16* const Ws = smem + BM * 64;

  const int z = blockIdx.z;
  const u16* __restrict__ A      = p.A[z];
  const u16* __restrict__ W      = p.W[z];
  const float* __restrict__ bias = p.Bv[z];
  const float scl = p.scl[z];

  const int tid = threadIdx.x;
  const int wave = tid >> 6, lane = tid & 63;
  const int quad = lane >> 4, l16 = lane & 15;
  const int bm = blockIdx.y * BM, bn = blockIdx.x * BN;
  const int wr = (wave >> 1) * (BM / 2), wc = (wave & 1) * (BN / 2);
  const int sr8 = lane >> 3;
  const int slc = (lane & 7) ^ sr8;           // logical k-chunk to fetch
  const int srow = wave * 8 + sr8;            // row within 32-row stripe

  f32x4 acc[MI][NJ];
#pragma unroll
  for (int i = 0; i < MI; i++)
#pragma unroll
    for (int j = 0; j < NJ; j++) acc[i][j] = {0.f, 0.f, 0.f, 0.f};

  const u16* Ab = A + (size_t)bm * K;
  const u16* Wb = W + (size_t)bn * K;

  for (int kt = 0; kt < K; kt += 64) {
    __syncthreads();  // previous iteration's LDS reads complete
#pragma unroll
    for (int i = 0; i < MI; i++)
      gl2lds16(Ab + (size_t)(i * 32 + srow) * K + kt + slc * 8,
               &As[(i * 32 + wave * 8) * 64]);
#pragma unroll
    for (int i = 0; i < NJ; i++)
      gl2lds16(Wb + (size_t)(i * 32 + srow) * K + kt + slc * 8,
               &Ws[(i * 32 + wave * 8) * 64]);
    __syncthreads();  // drains vmcnt (async loads) + LDS visible

#pragma unroll
    for (int ks = 0; ks < 2; ks++) {
      const int ch = ks * 4 + quad;  // logical chunk of this fragment
      s16x8 a[MI], b[NJ];
#pragma unroll
      for (int t = 0; t < MI; t++)
        a[t] = *(const s16x8*)&As[(wr + t * 16 + l16) * 64 + ((ch ^ (l16 & 7)) << 3)];
#pragma unroll
      for (int t = 0; t < NJ; t++)
        b[t] = *(const s16x8*)&Ws[(wc + t * 16 + l16) * 64 + ((ch ^ (l16 & 7)) << 3)];
#pragma unroll
      for (int i = 0; i < MI; i++)
#pragma unroll
        for (int j = 0; j < NJ; j++)
          acc[i][j] = __builtin_amdgcn_mfma_f32_16x16x32_bf16(a[i], b[j], acc[i][j], 0, 0, 0);
    }
  }

  if (VT && z == 2) {
    // ---- fused V transpose: acc -> LDS [col][row] -> Vt[d-row][s] ----
    __syncthreads();               // all waves done reading As/Ws
    u16* const T = smem;           // [BN][TS]
#pragma unroll
    for (int j = 0; j < NJ; j++) {
      const int c = wc + j * 16 + l16;
      const float bv = bias[bn + c];
#pragma unroll
      for (int i = 0; i < MI; i++) {
        const int r0 = wr + i * 16 + quad * 4;
        u16x4 t4;
#pragma unroll
        for (int r = 0; r < 4; r++) t4[r] = f2bf((acc[i][j][r] + bv) * scl);
        *(u16x4*)&T[c * TS + r0] = t4;
      }
    }
    __syncthreads();
    // thread -> (c = tid>>1, half = tid&1): 64 contiguous s per thread
    const int c = tid >> 1, half = tid & 1;
    const int b_ = bm >> 11;                 // batch (2048 rows each, 128 | 2048)
    const int sb = (bm & 2047) + half * 64;  // s within batch
    u16* dst = p.vt + (size_t)(b_ * 1024 + bn + c) * S_LEN + sb;
    const u16* srcT = &T[c * TS + half * 64];
#pragma unroll
    for (int k = 0; k < 8; k++)
      *(s16x8*)(dst + k * 8) = *(const s16x8*)(srcT + k * 8);
  } else {
    // epilogue: C/D layout row = quad*4 + reg, col = lane&15
#pragma unroll
    for (int j = 0; j < NJ; j++) {
      const int col = bn + wc + j * 16 + l16;
      const float bv = bias[col];
#pragma unroll
      for (int i = 0; i < MI; i++) {
        const int row0 = bm + wr + i * 16 + quad * 4;
#pragma unroll
        for (int r = 0; r < 4; r++) {
          const float val = (acc[i][j][r] + bv) * scl;
          if (OUT_F32)
            ((float*)p.C[z])[(size_t)(row0 + r) * N + col] = val;
          else
            ((u16*)p.C[z])[(size_t)(row0 + r) * N + col] = f2bf(val);
        }
      }
    }
  }
}

// ---------------------------------------------------------------------------
// Flash attention R16: QBLK=64, 512 threads = 8 waves = 2 q-tiles(32 rows) x
// 4 kv-quarters(32 kv). LDS 40KB; __launch_bounds__(512,4) (VGPR cap 128;
// expect natural ~64 -> 3-4 blocks/CU). Grid (32,32) = 1024 blocks.
// Two-stage end merge: waves 4-7 dump O/l; 0-3 add; 2-3 dump; 0-1 finalize.
// ---------------------------------------------------------------------------
__global__ __launch_bounds__(512, 4) void attn_kernel(const u16* __restrict__ Qp,
                                                      const u16* __restrict__ Kp,
                                                      const u16* __restrict__ Vt,
                                                      u16* __restrict__ AO) {
  __shared__ u16 smem[20480];    // 40 KB
  u16* const Qs = smem;          // [q:64][d:64]    8 KB, 8-chunk XOR swizzle
  u16* const Ks = smem + 4096;   // [kv:128][d:64] 16 KB, 8-chunk XOR swizzle
  u16* const Vs = smem + 12288;  // [d:64][kv:128] 16 KB, 16-chunk XOR swizzle

  const int tid = threadIdx.x;
  const int wave = tid >> 6, lane = tid & 63;
  const int quad = lane >> 4, l16 = lane & 15;
  const int bh = blockIdx.y, b = bh >> 4, h = bh & 15;
  const int s0 = blockIdx.x * 64;
  const int qw = wave & 1;        // q-tile index (32 rows each)
  const int kvq = wave >> 1;      // kv quarter (32 kv rows each)

  const int sr = tid >> 3, sc8 = tid & 7;     // sr in [0,64)
  const int sxor = (sc8 ^ (sr & 7)) << 3;
  const int vr = tid >> 4, vc = tid & 15;     // vr in [0,32)
  const int vxor = (vc ^ (vr & 15)) << 3;

  // ---- Q stage (64 rows, one shot) + per-wave fragments (32 rows) ----
  {
    s16x8 qv = *(const s16x8*)(Qp + (size_t)(b * S_LEN + s0 + sr) * DMODEL + h * 64 + sc8 * 8);
    *(s16x8*)&Qs[sr * 64 + sxor] = qv;
  }
  __syncthreads();

  s16x8 aq[2][2];  // [ks][rt]
#pragma unroll
  for (int ks = 0; ks < 2; ks++)
#pragma unroll
    for (int rt = 0; rt < 2; rt++) {
      const int row = qw * 32 + rt * 16 + l16;
      const int ch = ks * 4 + quad;
      aq[ks][rt] = *(const s16x8*)&Qs[row * 64 + ((ch ^ (l16 & 7)) << 3)];
    }

  // ---- K/V register prefetch for kt=0 (cooperative staging) ----
  s16x8 kv[2], vv[2];
#pragma unroll
  for (int i = 0; i < 2; i++)
    kv[i] = *(const s16x8*)(Kp + (size_t)(b * S_LEN + i * 64 + sr) * DMODEL + h * 64 + sc8 * 8);
#pragma unroll
  for (int i = 0; i < 2; i++)
    vv[i] = *(const s16x8*)(Vt + (size_t)(bh * 64 + i * 32 + vr) * S_LEN + vc * 8);

  f32x4 o[2][4];
  float l_r[2] = {0.f, 0.f};
#pragma unroll
  for (int rt = 0; rt < 2; rt++)
#pragma unroll
    for (int dt = 0; dt < 4; dt++) o[rt][dt] = {0.f, 0.f, 0.f, 0.f};

  const f32x4 zf = {0.f, 0.f, 0.f, 0.f};

  for (int kt = 0; kt < S_LEN; kt += 128) {
    __syncthreads();
#pragma unroll
    for (int i = 0; i < 2; i++)
      *(s16x8*)&Ks[(i * 64 + sr) * 64 + sxor] = kv[i];
#pragma unroll
    for (int i = 0; i < 2; i++)
      *(s16x8*)&Vs[(i * 32 + vr) * 128 + vxor] = vv[i];
    __syncthreads();

    if (kt + 128 < S_LEN) {
      const int k2 = kt + 128;
#pragma unroll
      for (int i = 0; i < 2; i++)
        kv[i] = *(const s16x8*)(Kp + (size_t)(b * S_LEN + k2 + i * 64 + sr) * DMODEL + h * 64 + sc8 * 8);
#pragma unroll
      for (int i = 0; i < 2; i++)
        vv[i] = *(const s16x8*)(Vt + (size_t)(bh * 64 + i * 32 + vr) * S_LEN + k2 + vc * 8);
    }

    // ---- this wave's kv quarter: rows kvq*32 .. kvq*32+31 (2 subtiles) ----
#pragma unroll
    for (int kvt = 0; kvt < 2; kvt++) {
      const int krow = kvq * 32 + kvt * 16 + l16;   // krow&7 == l16&7
      s16x8 ak0 = *(const s16x8*)&Ks[krow * 64 + (((0 + quad) ^ (l16 & 7)) << 3)];
      s16x8 ak1 = *(const s16x8*)&Ks[krow * 64 + (((4 + quad) ^ (l16 & 7)) << 3)];

      s16x4 pf[2];
#pragma unroll
      for (int rt = 0; rt < 2; rt++) {
        f32x4 sA;
        sA = __builtin_amdgcn_mfma_f32_16x16x32_bf16(ak0, aq[0][rt], zf, 0, 0, 0);
        sA = __builtin_amdgcn_mfma_f32_16x16x32_bf16(ak1, aq[1][rt], sA, 0, 0, 0);

        union { float f; uint32_t u; } e0, e1, e2, e3;
        e0.f = __builtin_amdgcn_exp2f(sA[0]);
        e1.f = __builtin_amdgcn_exp2f(sA[1]);
        e2.f = __builtin_amdgcn_exp2f(sA[2]);
        e3.f = __builtin_amdgcn_exp2f(sA[3]);
        l_r[rt] += (((e0.f + e1.f) + e2.f) + e3.f);

        union { uint32_t u[2]; s16x4 v; } pk;
        pk.u[0] = __builtin_amdgcn_perm(e1.u + 0x8000u, e0.u + 0x8000u, 0x07060302u);
        pk.u[1] = __builtin_amdgcn_perm(e3.u + 0x8000u, e2.u + 0x8000u, 0x07060302u);
        pf[rt] = pk.v;
      }

      const int ch = kvq * 4 + kvt * 2 + (quad >> 1);
#pragma unroll
      for (int dt = 0; dt < 4; dt++) {
        const int row = dt * 16 + l16;
        s16x4 bv = *(const s16x4*)&Vs[row * 128 + ((ch ^ l16) << 3) + (quad & 1) * 4];
        o[0][dt] = __builtin_amdgcn_mfma_f32_16x16x16bf16_1k(pf[0], bv, o[0][dt], 0, 0, 0);
        o[1][dt] = __builtin_amdgcn_mfma_f32_16x16x16bf16_1k(pf[1], bv, o[1][dt], 0, 0, 0);
      }
    }
  }

  // intra-wave l reduction (sum over quads -> value depends on l16 only)
#pragma unroll
  for (int rt = 0; rt < 2; rt++) {
    l_r[rt] += __shfl_xor(l_r[rt], 16);
    l_r[rt] += __shfl_xor(l_r[rt], 32);
  }

  // ---- two-stage cross-quarter merge through reused LDS ----
  // layout: mrgO[slot:4][rt*4+dt:8][lane:64] f32x4 (32 KB), mrgL[slot:4][rt:2][lane] (2 KB)
  f32x4* const mrgO = (f32x4*)smem;
  float* const mrgL = (float*)(smem + 16384);  // 32 KB offset (u16 idx 16384)
  __syncthreads();  // all LDS reads of last ktile complete
  if (wave >= 4) {   // kvq 2,3 -> slots 0..3
    const int slot = wave - 4;
#pragma unroll
    for (int rt = 0; rt < 2; rt++) {
#pragma unroll
      for (int dt = 0; dt < 4; dt++)
        mrgO[(slot * 8 + rt * 4 + dt) * 64 + lane] = o[rt][dt];
      mrgL[(slot * 2 + rt) * 64 + lane] = l_r[rt];
    }
  }
  __syncthreads();
  if (wave < 4) {    // merge partner wave+4 (same qw, kvq+2)
    const int slot = wave;
#pragma unroll
    for (int rt = 0; rt < 2; rt++) {
#pragma unroll
      for (int dt = 0; dt < 4; dt++)
        o[rt][dt] += mrgO[(slot * 8 + rt * 4 + dt) * 64 + lane];
      l_r[rt] += mrgL[(slot * 2 + rt) * 64 + lane];
    }
  }
  __syncthreads();
  if (wave >= 2 && wave < 4) {  // kvq==1 -> slots 0,1
    const int slot = wave - 2;
#pragma unroll
    for (int rt = 0; rt < 2; rt++) {
#pragma unroll
      for (int dt = 0; dt < 4; dt++)
        mrgO[(slot * 8 + rt * 4 + dt) * 64 + lane] = o[rt][dt];
      mrgL[(slot * 2 + rt) * 64 + lane] = l_r[rt];
    }
  }
  __syncthreads();
  if (wave < 2) {    // final: merge wave+2, normalize, store (qw == wave)
    const int slot = wave;
#pragma unroll
    for (int rt = 0; rt < 2; rt++) {
#pragma unroll
      for (int dt = 0; dt < 4; dt++)
        o[rt][dt] += mrgO[(slot * 8 + rt * 4 + dt) * 64 + lane];
      l_r[rt] += mrgL[(slot * 2 + rt) * 64 + lane];
    }
#pragma unroll
    for (int rt = 0; rt < 2; rt++) {
#pragma unroll
      for (int r = 0; r < 4; r++) {
        const float linv = 1.f / __shfl(l_r[rt], quad * 4 + r);
        const int row = s0 + wave * 32 + rt * 16 + quad * 4 + r;
#pragma unroll
        for (int dt = 0; dt < 4; dt++)
          AO[(size_t)(b * S_LEN + row) * DMODEL + h * 64 + dt * 16 + l16] =
              f2bf(o[rt][dt][r] * linv);
      }
    }
  }
}

// ---------------------------------------------------------------------------
extern "C" void kernel_launch(void* const* d_in, const int* in_sizes, int n_in,
                              void* d_out, int out_size, void* d_ws, size_t ws_size,
                              hipStream_t stream) {
  const float* query = (const float*)d_in[0];
  const float* key_  = (const float*)d_in[1];
  const float* value = (const float*)d_in[2];
  const float* W_q = (const float*)d_in[3];
  const float* b_q = (const float*)d_in[4];
  const float* W_k = (const float*)d_in[5];
  const float* b_k = (const float*)d_in[6];
  const float* W_v = (const float*)d_in[7];
  const float* b_v = (const float*)d_in[8];
  const float* W_o = (const float*)d_in[9];
  const float* b_o = (const float*)d_in[10];
  float* out = (float*)d_out;

  const int M = 2 * S_LEN;  // 4096
  const int N = DMODEL, K = DMODEL;
  const size_t WSZ = (size_t)DMODEL * DMODEL;   // 1,048,576
  const size_t SZ  = (size_t)M * DMODEL;        // 4,194,304

  u16* Wqb = (u16*)d_ws;         // 4 bf16 weights
  u16* Wkb = Wqb + WSZ;
  u16* Wvb = Wkb + WSZ;
  u16* Wob = Wvb + WSZ;
  u16* Qa  = Wob + WSZ;          // bf16 inputs (dead after QKV GEMM)
  u16* Ka  = Qa + SZ;
  u16* Va  = Ka + SZ;
  u16* Qp  = Va + SZ;            // projections
  u16* Kp  = Qp + SZ;
  u16* Vt  = Kp + SZ;            // [B,H,Dh,S] -- written directly by V-GEMM (VT path)
  u16* AO  = Qp;                 // aliases Qp (per-block disjoint read->write)

  Cvt7 cw;
  cw.s[0] = W_q;   cw.d[0] = Wqb; cw.n[0] = (int)WSZ;
  cw.s[1] = W_k;   cw.d[1] = Wkb; cw.n[1] = (int)WSZ;
  cw.s[2] = W_v;   cw.d[2] = Wvb; cw.n[2] = (int)WSZ;
  cw.s[3] = W_o;   cw.d[3] = Wob; cw.n[3] = (int)WSZ;
  cw.s[4] = query; cw.d[4] = Qa;  cw.n[4] = (int)SZ;
  cw.s[5] = key_;  cw.d[5] = Ka;  cw.n[5] = (int)SZ;
  cw.s[6] = value; cw.d[6] = Va;  cw.n[6] = (int)SZ;
  cvt7<<<dim3((int)(SZ / 2048), 7), 256, 0, stream>>>(cw);

  GemmBatch p1;
  p1.A[0] = Qa; p1.W[0] = Wqb; p1.Bv[0] = b_q; p1.C[0] = Qp;
  p1.A[1] = Ka; p1.W[1] = Wkb; p1.Bv[1] = b_k; p1.C[1] = Kp;
  p1.A[2] = Va; p1.W[2] = Wvb; p1.Bv[2] = b_v; p1.C[2] = Vt;  // unused (VT path)
  p1.vt = Vt;
  p1.scl[0] = 0.03125f * LOG2E;  // d_model^-0.5 * log2(e) folded into Q (fp32)
  p1.scl[1] = 1.0f;
  p1.scl[2] = 1.0f;
  gemm_bt<128, 128, false, true><<<dim3(N / 128, M / 128, 3), 256, 0, stream>>>(p1, M, N, K);

  attn_kernel<<<dim3(S_LEN / 64, 32), 512, 0, stream>>>(Qp, Kp, Vt, AO);

  GemmBatch p2;
  p2.A[0] = AO; p2.W[0] = Wob; p2.Bv[0] = b_o; p2.C[0] = out;
  p2.A[1] = AO; p2.W[1] = Wob; p2.Bv[1] = b_o; p2.C[1] = out;
  p2.A[2] = AO; p2.W[2] = Wob; p2.Bv[2] = b_o; p2.C[2] = out;
  p2.vt = nullptr;
  p2.scl[0] = 1.0f; p2.scl[1] = 1.0f; p2.scl[2] = 1.0f;
  gemm_bt<64, 64, true, false><<<dim3(N / 64, M / 64, 1), 256, 0, stream>>>(p2, M, N, K);
}

// Round 10
// 221.745 us; speedup vs baseline: 3.6745x; 1.0333x over previous
//
#include <hip/hip_runtime.h>
#include <stdint.h>

// MultiHeadAttention: B=2, S=2048, D=1024, H=16, Dh=64. fp32 in/out, bf16 MFMA inside.
// R17: revert attn to R13 (best measured, 54.2us; R15/R16 QBLK=64 experiments
// regressed and are abandoned) + XCD-aware block swizzle (T1) on all 3 heavy
// kernels. HW round-robins wgid%8 across XCDs; bijective remap lid =
// (w&7)*(nwg/8)+(w>>3) gives each XCD a contiguous tile range:
//  - attn: 4 bh/XCD -> K/V working set 2MB, L2-resident (was L3/HBM; FETCH 70MB)
//  - QKV GEMM: 4 bm-rows/XCD -> 4 A-panels + full W = 3MB < 4MB L2
//  - O GEMM: 8 bm-rows/XCD -> 1MB A + 2MB W < L2
// Carried: Q pre-scale in GEMM epilogue, raw v_exp_f32, v_perm P-pack, fused
// V-transpose, 64x64 O-GEMM.

typedef unsigned short u16;
typedef short s16x8 __attribute__((ext_vector_type(8)));   // 8 bf16 (4 VGPR)
typedef short s16x4 __attribute__((ext_vector_type(4)));   // 4 bf16 (2 VGPR)
typedef float f32x4 __attribute__((ext_vector_type(4)));
typedef u16 u16x4 __attribute__((ext_vector_type(4)));

#define S_LEN 2048
#define DMODEL 1024
#define LOG2E 1.44269504088896340736f

__device__ __forceinline__ u16 f2bf(float f) {
  union { float f; uint32_t u; } v; v.f = f;
  return (u16)((v.u + 0x8000u) >> 16);
}

__device__ __forceinline__ s16x8 ld8f(const float* s) {  // 8 fp32 -> 8 bf16
  f32x4 a = *(const f32x4*)s;
  f32x4 b = *(const f32x4*)(s + 4);
  s16x8 r;
  r[0] = (short)f2bf(a[0]); r[1] = (short)f2bf(a[1]);
  r[2] = (short)f2bf(a[2]); r[3] = (short)f2bf(a[3]);
  r[4] = (short)f2bf(b[0]); r[5] = (short)f2bf(b[1]);
  r[6] = (short)f2bf(b[2]); r[7] = (short)f2bf(b[3]);
  return r;
}

// async global->LDS, 16B/lane; HW scatters lane i to ldsbase + i*16
__device__ __forceinline__ void gl2lds16(const u16* g, u16* l) {
  __builtin_amdgcn_global_load_lds(
      (const __attribute__((address_space(1))) uint32_t*)g,
      (__attribute__((address_space(3))) uint32_t*)l, 16, 0, 0);
}

// ---------------------------------------------------------------------------
// fp32 -> bf16 conversion: 4 weights (1M elem) + 3 activations (4.19M elem).
// ---------------------------------------------------------------------------
struct Cvt7 { const float* s[7]; u16* d[7]; int n[7]; };

__global__ __launch_bounds__(256) void cvt7(Cvt7 p) {
  const int z = blockIdx.y;
  const int idx = blockIdx.x * 256 + threadIdx.x;
  if (idx * 8 < p.n[z])
    *(s16x8*)(p.d[z] + (size_t)idx * 8) = ld8f(p.s[z] + (size_t)idx * 8);
}

// ---------------------------------------------------------------------------
// GEMM: C[M,N] = (A[M,K] @ W[N,K]^T + bias[N]) * scl; A,W bf16, bias fp32.
// scl=1.0 for all but the Q projection (score scale folded in, fp32 pre-round).
// Template: BM x BN tile (BK=64 fixed), 4 waves as 2x2 of (BM/2 x BN/2).
// OUT_F32: fp32 C (O projection). VT: z==2 writes transposed bf16 to p.vt.
// XCD swizzle: lid = (w&7)*(nwg/8) + w/8 groups contiguous bm-rows per XCD.
// ---------------------------------------------------------------------------
struct GemmBatch {
  const u16* A[3]; const u16* W[3]; const float* Bv[3]; void* C[3];
  u16* vt;       // VT destination: Vt[(b*16+h)*64+dh][s], row stride S_LEN
  float scl[3];  // epilogue scale (fp32, applied before f2bf round)
};

template <int BM, int BN, bool OUT_F32, bool VT>
__global__ __launch_bounds__(256) void gemm_bt(GemmBatch p, int M, int N, int K) {
  static_assert(!VT || (BM == 128 && BN == 128), "VT epilogue assumes 128x128");
  constexpr int MI = BM / 32, NJ = BN / 32;   // fragment repeats per wave
  constexpr int TS = BM + 8;                  // VT transpose stride (u16), 16B-aligned
  constexpr int AB = BM * 64 + BN * 64;
  constexpr int TB = VT ? BN * TS : 0;
  constexpr int SM = AB > TB ? AB : TB;
  __shared__ u16 smem[SM];
  u16* const As = smem;
  u16* const Ws = smem + BM * 64;

  const int z = blockIdx.z;
  const u16* __restrict__ A      = p.A[z];
  const u16* __restrict__ W      = p.W[z];
  const float* __restrict__ bias = p.Bv[z];
  const float scl = p.scl[z];

  const int tid = threadIdx.x;
  const int wave = tid >> 6, lane = tid & 63;
  const int quad = lane >> 4, l16 = lane & 15;

  // XCD-aware bijective swizzle (nwg divisible by 8 for all our grids)
  const int nwg = gridDim.x * gridDim.y;
  const int w = blockIdx.x + gridDim.x * blockIdx.y;
  const int lid = (w & 7) * (nwg >> 3) + (w >> 3);
  const int bm = (lid / gridDim.x) * BM, bn = (lid % gridDim.x) * BN;

  const int wr = (wave >> 1) * (BM / 2), wc = (wave & 1) * (BN / 2);
  const int sr8 = lane >> 3;
  const int slc = (lane & 7) ^ sr8;           // logical k-chunk to fetch
  const int srow = wave * 8 + sr8;            // row within 32-row stripe

  f32x4 acc[MI][NJ];
#pragma unroll
  for (int i = 0; i < MI; i++)
#pragma unroll
    for (int j = 0; j < NJ; j++) acc[i][j] = {0.f, 0.f, 0.f, 0.f};

  const u16* Ab = A + (size_t)bm * K;
  const u16* Wb = W + (size_t)bn * K;

  for (int kt = 0; kt < K; kt += 64) {
    __syncthreads();  // previous iteration's LDS reads complete
#pragma unroll
    for (int i = 0; i < MI; i++)
      gl2lds16(Ab + (size_t)(i * 32 + srow) * K + kt + slc * 8,
               &As[(i * 32 + wave * 8) * 64]);
#pragma unroll
    for (int i = 0; i < NJ; i++)
      gl2lds16(Wb + (size_t)(i * 32 + srow) * K + kt + slc * 8,
               &Ws[(i * 32 + wave * 8) * 64]);
    __syncthreads();  // drains vmcnt (async loads) + LDS visible

#pragma unroll
    for (int ks = 0; ks < 2; ks++) {
      const int ch = ks * 4 + quad;  // logical chunk of this fragment
      s16x8 a[MI], b[NJ];
#pragma unroll
      for (int t = 0; t < MI; t++)
        a[t] = *(const s16x8*)&As[(wr + t * 16 + l16) * 64 + ((ch ^ (l16 & 7)) << 3)];
#pragma unroll
      for (int t = 0; t < NJ; t++)
        b[t] = *(const s16x8*)&Ws[(wc + t * 16 + l16) * 64 + ((ch ^ (l16 & 7)) << 3)];
#pragma unroll
      for (int i = 0; i < MI; i++)
#pragma unroll
        for (int j = 0; j < NJ; j++)
          acc[i][j] = __builtin_amdgcn_mfma_f32_16x16x32_bf16(a[i], b[j], acc[i][j], 0, 0, 0);
    }
  }

  if (VT && z == 2) {
    // ---- fused V transpose: acc -> LDS [col][row] -> Vt[d-row][s] ----
    __syncthreads();               // all waves done reading As/Ws
    u16* const T = smem;           // [BN][TS]
#pragma unroll
    for (int j = 0; j < NJ; j++) {
      const int c = wc + j * 16 + l16;
      const float bv = bias[bn + c];
#pragma unroll
      for (int i = 0; i < MI; i++) {
        const int r0 = wr + i * 16 + quad * 4;
        u16x4 t4;
#pragma unroll
        for (int r = 0; r < 4; r++) t4[r] = f2bf((acc[i][j][r] + bv) * scl);
        *(u16x4*)&T[c * TS + r0] = t4;
      }
    }
    __syncthreads();
    // thread -> (c = tid>>1, half = tid&1): 64 contiguous s per thread
    const int c = tid >> 1, half = tid & 1;
    const int b_ = bm >> 11;                 // batch (2048 rows each, 128 | 2048)
    const int sb = (bm & 2047) + half * 64;  // s within batch
    u16* dst = p.vt + (size_t)(b_ * 1024 + bn + c) * S_LEN + sb;
    const u16* srcT = &T[c * TS + half * 64];
#pragma unroll
    for (int k = 0; k < 8; k++)
      *(s16x8*)(dst + k * 8) = *(const s16x8*)(srcT + k * 8);
  } else {
    // epilogue: C/D layout row = quad*4 + reg, col = lane&15
#pragma unroll
    for (int j = 0; j < NJ; j++) {
      const int col = bn + wc + j * 16 + l16;
      const float bv = bias[col];
#pragma unroll
      for (int i = 0; i < MI; i++) {
        const int row0 = bm + wr + i * 16 + quad * 4;
#pragma unroll
        for (int r = 0; r < 4; r++) {
          const float val = (acc[i][j][r] + bv) * scl;
          if (OUT_F32)
            ((float*)p.C[z])[(size_t)(row0 + r) * N + col] = val;
          else
            ((u16*)p.C[z])[(size_t)(row0 + r) * N + col] = f2bf(val);
        }
      }
    }
  }
}

// ---------------------------------------------------------------------------
// Flash attention (R13 structure, proven 54.2us): 512 threads = 8 waves =
// 4 q-tiles(32 rows) x 2 kv-halves. Grid (16,32); 48KB LDS. XCD swizzle:
// 4 bh per XCD -> K/V (2MB) L2-resident.
// ---------------------------------------------------------------------------
__global__ __launch_bounds__(512, 4) void attn_kernel(const u16* __restrict__ Qp,
                                                      const u16* __restrict__ Kp,
                                                      const u16* __restrict__ Vt,
                                                      u16* __restrict__ AO) {
  __shared__ u16 smem[24576];    // 48 KB
  u16* const Qs = smem;          // [q:128][d:64]  16 KB, 8-chunk XOR swizzle
  u16* const Ks = smem + 8192;   // [kv:128][d:64] 16 KB, 8-chunk XOR swizzle
  u16* const Vs = smem + 16384;  // [d:64][kv:128] 16 KB, 16-chunk XOR swizzle

  const int tid = threadIdx.x;
  const int wave = tid >> 6, lane = tid & 63;
  const int quad = lane >> 4, l16 = lane & 15;

  // XCD swizzle: w = x + 16y, nwg=512 -> 64 lids/XCD -> bh in [4j,4j+4)
  const int w = blockIdx.x + gridDim.x * blockIdx.y;
  const int lid = (w & 7) * 64 + (w >> 3);
  const int bh = lid >> 4, b = bh >> 4, h = bh & 15;
  const int s0 = (lid & 15) * 128;

  const int qw = wave & 3;        // q-tile index (32 rows each)
  const int kvh = wave >> 2;      // kv half (64 kv rows each)

  const int sr = tid >> 3, sc8 = tid & 7;
  const int sxor = (sc8 ^ (sr & 7)) << 3;
  const int vr = tid >> 4, vc = tid & 15;
  const int vxor = (vc ^ (vr & 15)) << 3;

  // ---- Q stage (cooperative, 128 rows) + per-wave fragments (32 rows) ----
#pragma unroll
  for (int i = 0; i < 2; i++) {
    const int rr = i * 64 + sr;
    s16x8 qv = *(const s16x8*)(Qp + (size_t)(b * S_LEN + s0 + rr) * DMODEL + h * 64 + sc8 * 8);
    *(s16x8*)&Qs[rr * 64 + sxor] = qv;
  }
  __syncthreads();

  s16x8 aq[2][2];  // [ks][rt]
#pragma unroll
  for (int ks = 0; ks < 2; ks++)
#pragma unroll
    for (int rt = 0; rt < 2; rt++) {
      const int row = qw * 32 + rt * 16 + l16;
      const int ch = ks * 4 + quad;
      aq[ks][rt] = *(const s16x8*)&Qs[row * 64 + ((ch ^ (l16 & 7)) << 3)];
    }

  // ---- K/V register prefetch for kt=0 (cooperative staging) ----
  s16x8 kv[2], vv[2];
#pragma unroll
  for (int i = 0; i < 2; i++)
    kv[i] = *(const s16x8*)(Kp + (size_t)(b * S_LEN + i * 64 + sr) * DMODEL + h * 64 + sc8 * 8);
#pragma unroll
  for (int i = 0; i < 2; i++)
    vv[i] = *(const s16x8*)(Vt + (size_t)(bh * 64 + i * 32 + vr) * S_LEN + vc * 8);

  f32x4 o[2][4];
  float l_r[2] = {0.f, 0.f};
#pragma unroll
  for (int rt = 0; rt < 2; rt++)
#pragma unroll
    for (int dt = 0; dt < 4; dt++) o[rt][dt] = {0.f, 0.f, 0.f, 0.f};

  const f32x4 zf = {0.f, 0.f, 0.f, 0.f};

  for (int kt = 0; kt < S_LEN; kt += 128) {
    __syncthreads();
#pragma unroll
    for (int i = 0; i < 2; i++)
      *(s16x8*)&Ks[(i * 64 + sr) * 64 + sxor] = kv[i];
#pragma unroll
    for (int i = 0; i < 2; i++)
      *(s16x8*)&Vs[(i * 32 + vr) * 128 + vxor] = vv[i];
    __syncthreads();

    if (kt + 128 < S_LEN) {
      const int k2 = kt + 128;
#pragma unroll
      for (int i = 0; i < 2; i++)
        kv[i] = *(const s16x8*)(Kp + (size_t)(b * S_LEN + k2 + i * 64 + sr) * DMODEL + h * 64 + sc8 * 8);
#pragma unroll
      for (int i = 0; i < 2; i++)
        vv[i] = *(const s16x8*)(Vt + (size_t)(bh * 64 + i * 32 + vr) * S_LEN + k2 + vc * 8);
    }

    // this wave's kv half: rows kvh*64 .. kvh*64+63 (4 subtiles of 16)
#pragma unroll
    for (int kvt = 0; kvt < 4; kvt++) {
      const int krow = kvh * 64 + kvt * 16 + l16;   // krow&7 == l16&7
      s16x8 ak0 = *(const s16x8*)&Ks[krow * 64 + (((0 + quad) ^ (l16 & 7)) << 3)];
      s16x8 ak1 = *(const s16x8*)&Ks[krow * 64 + (((4 + quad) ^ (l16 & 7)) << 3)];

      s16x4 pf[2];
#pragma unroll
      for (int rt = 0; rt < 2; rt++) {
        f32x4 sA;
        sA = __builtin_amdgcn_mfma_f32_16x16x32_bf16(ak0, aq[0][rt], zf, 0, 0, 0);
        sA = __builtin_amdgcn_mfma_f32_16x16x32_bf16(ak1, aq[1][rt], sA, 0, 0, 0);

        union { float f; uint32_t u; } e0, e1, e2, e3;
        e0.f = __builtin_amdgcn_exp2f(sA[0]);
        e1.f = __builtin_amdgcn_exp2f(sA[1]);
        e2.f = __builtin_amdgcn_exp2f(sA[2]);
        e3.f = __builtin_amdgcn_exp2f(sA[3]);
        l_r[rt] += (((e0.f + e1.f) + e2.f) + e3.f);

        union { uint32_t u[2]; s16x4 v; } pk;
        pk.u[0] = __builtin_amdgcn_perm(e1.u + 0x8000u, e0.u + 0x8000u, 0x07060302u);
        pk.u[1] = __builtin_amdgcn_perm(e3.u + 0x8000u, e2.u + 0x8000u, 0x07060302u);
        pf[rt] = pk.v;
      }

      const int ch = kvh * 8 + kvt * 2 + (quad >> 1);
#pragma unroll
      for (int dt = 0; dt < 4; dt++) {
        const int row = dt * 16 + l16;
        s16x4 bv = *(const s16x4*)&Vs[row * 128 + ((ch ^ l16) << 3) + (quad & 1) * 4];
        o[0][dt] = __builtin_amdgcn_mfma_f32_16x16x16bf16_1k(pf[0], bv, o[0][dt], 0, 0, 0);
        o[1][dt] = __builtin_amdgcn_mfma_f32_16x16x16bf16_1k(pf[1], bv, o[1][dt], 0, 0, 0);
      }
    }
  }

  // intra-wave l reduction (sum over quads -> value depends on l16 only)
#pragma unroll
  for (int rt = 0; rt < 2; rt++) {
    l_r[rt] += __shfl_xor(l_r[rt], 16);
    l_r[rt] += __shfl_xor(l_r[rt], 32);
  }

  // ---- cross-half merge: waves 4..7 dump O/l into reused staging LDS ----
  __syncthreads();  // all LDS reads of last ktile complete
  f32x4* const mrgO = (f32x4*)smem;            // [rt*4+dt][w*64+lane], 32 KB
  float* const mrgL = (float*)smem + 8192;     // [rt][w*64+lane], 2 KB @ 32 KB
  if (wave >= 4) {
    const int w4 = wave - 4;
#pragma unroll
    for (int rt = 0; rt < 2; rt++) {
#pragma unroll
      for (int dt = 0; dt < 4; dt++)
        mrgO[(rt * 4 + dt) * 256 + w4 * 64 + lane] = o[rt][dt];
      mrgL[rt * 256 + w4 * 64 + lane] = l_r[rt];
    }
  }
  __syncthreads();
  if (wave < 4) {
#pragma unroll
    for (int rt = 0; rt < 2; rt++) {
#pragma unroll
      for (int dt = 0; dt < 4; dt++) {
        f32x4 ov = mrgO[(rt * 4 + dt) * 256 + wave * 64 + lane];
        o[rt][dt] += ov;
      }
      l_r[rt] += mrgL[rt * 256 + wave * 64 + lane];
    }
#pragma unroll
    for (int rt = 0; rt < 2; rt++) {
#pragma unroll
      for (int r = 0; r < 4; r++) {
        const float linv = 1.f / __shfl(l_r[rt], quad * 4 + r);
        const int row = s0 + qw * 32 + rt * 16 + quad * 4 + r;
#pragma unroll
        for (int dt = 0; dt < 4; dt++)
          AO[(size_t)(b * S_LEN + row) * DMODEL + h * 64 + dt * 16 + l16] =
              f2bf(o[rt][dt][r] * linv);
      }
    }
  }
}

// ---------------------------------------------------------------------------
extern "C" void kernel_launch(void* const* d_in, const int* in_sizes, int n_in,
                              void* d_out, int out_size, void* d_ws, size_t ws_size,
                              hipStream_t stream) {
  const float* query = (const float*)d_in[0];
  const float* key_  = (const float*)d_in[1];
  const float* value = (const float*)d_in[2];
  const float* W_q = (const float*)d_in[3];
  const float* b_q = (const float*)d_in[4];
  const float* W_k = (const float*)d_in[5];
  const float* b_k = (const float*)d_in[6];
  const float* W_v = (const float*)d_in[7];
  const float* b_v = (const float*)d_in[8];
  const float* W_o = (const float*)d_in[9];
  const float* b_o = (const float*)d_in[10];
  float* out = (float*)d_out;

  const int M = 2 * S_LEN;  // 4096
  const int N = DMODEL, K = DMODEL;
  const size_t WSZ = (size_t)DMODEL * DMODEL;   // 1,048,576
  const size_t SZ  = (size_t)M * DMODEL;        // 4,194,304

  u16* Wqb = (u16*)d_ws;         // 4 bf16 weights
  u16* Wkb = Wqb + WSZ;
  u16* Wvb = Wkb + WSZ;
  u16* Wob = Wvb + WSZ;
  u16* Qa  = Wob + WSZ;          // bf16 inputs (dead after QKV GEMM)
  u16* Ka  = Qa + SZ;
  u16* Va  = Ka + SZ;
  u16* Qp  = Va + SZ;            // projections
  u16* Kp  = Qp + SZ;
  u16* Vt  = Kp + SZ;            // [B,H,Dh,S] -- written directly by V-GEMM (VT path)
  u16* AO  = Qp;                 // aliases Qp (per-block disjoint read->write)

  Cvt7 cw;
  cw.s[0] = W_q;   cw.d[0] = Wqb; cw.n[0] = (int)WSZ;
  cw.s[1] = W_k;   cw.d[1] = Wkb; cw.n[1] = (int)WSZ;
  cw.s[2] = W_v;   cw.d[2] = Wvb; cw.n[2] = (int)WSZ;
  cw.s[3] = W_o;   cw.d[3] = Wob; cw.n[3] = (int)WSZ;
  cw.s[4] = query; cw.d[4] = Qa;  cw.n[4] = (int)SZ;
  cw.s[5] = key_;  cw.d[5] = Ka;  cw.n[5] = (int)SZ;
  cw.s[6] = value; cw.d[6] = Va;  cw.n[6] = (int)SZ;
  cvt7<<<dim3((int)(SZ / 2048), 7), 256, 0, stream>>>(cw);

  GemmBatch p1;
  p1.A[0] = Qa; p1.W[0] = Wqb; p1.Bv[0] = b_q; p1.C[0] = Qp;
  p1.A[1] = Ka; p1.W[1] = Wkb; p1.Bv[1] = b_k; p1.C[1] = Kp;
  p1.A[2] = Va; p1.W[2] = Wvb; p1.Bv[2] = b_v; p1.C[2] = Vt;  // unused (VT path)
  p1.vt = Vt;
  p1.scl[0] = 0.03125f * LOG2E;  // d_model^-0.5 * log2(e) folded into Q (fp32)
  p1.scl[1] = 1.0f;
  p1.scl[2] = 1.0f;
  gemm_bt<128, 128, false, true><<<dim3(N / 128, M / 128, 3), 256, 0, stream>>>(p1, M, N, K);

  attn_kernel<<<dim3(S_LEN / 128, 32), 512, 0, stream>>>(Qp, Kp, Vt, AO);

  GemmBatch p2;
  p2.A[0] = AO; p2.W[0] = Wob; p2.Bv[0] = b_o; p2.C[0] = out;
  p2.A[1] = AO; p2.W[1] = Wob; p2.Bv[1] = b_o; p2.C[1] = out;
  p2.A[2] = AO; p2.W[2] = Wob; p2.Bv[2] = b_o; p2.C[2] = out;
  p2.vt = nullptr;
  p2.scl[0] = 1.0f; p2.scl[1] = 1.0f; p2.scl[2] = 1.0f;
  gemm_bt<64, 64, true, false><<<dim3(N / 64, M / 64, 1), 256, 0, stream>>>(p2, M, N, K);
}

// Round 11
// 219.509 us; speedup vs baseline: 3.7120x; 1.0102x over previous
//
#include <hip/hip_runtime.h>
#include <stdint.h>

// MultiHeadAttention: B=2, S=2048, D=1024, H=16, Dh=64. fp32 in/out, bf16 MFMA inside.
// R18: QKV GEMM tile 128x128 -> 128x64 (grid 16x32x3 = 1536 blocks = 5-6/CU vs 3;
// same kernel template, zero new scheduling code). Theory: gemm1 runs 3-4x above
// its FLOP/L2 floors at 3 blocks/CU -> latency-bound; more co-resident blocks hide
// it (same mechanism as R11's O-GEMM 64^2 win). VT epilogue generalized to BN=64.
// attn: Q fragments loaded directly from global (bit-identical values; Qs buffer
// + initial barrier deleted, LDS 48->34KB). All else R17.

typedef unsigned short u16;
typedef short s16x8 __attribute__((ext_vector_type(8)));   // 8 bf16 (4 VGPR)
typedef short s16x4 __attribute__((ext_vector_type(4)));   // 4 bf16 (2 VGPR)
typedef float f32x4 __attribute__((ext_vector_type(4)));
typedef u16 u16x4 __attribute__((ext_vector_type(4)));

#define S_LEN 2048
#define DMODEL 1024
#define LOG2E 1.44269504088896340736f

__device__ __forceinline__ u16 f2bf(float f) {
  union { float f; uint32_t u; } v; v.f = f;
  return (u16)((v.u + 0x8000u) >> 16);
}

__device__ __forceinline__ s16x8 ld8f(const float* s) {  // 8 fp32 -> 8 bf16
  f32x4 a = *(const f32x4*)s;
  f32x4 b = *(const f32x4*)(s + 4);
  s16x8 r;
  r[0] = (short)f2bf(a[0]); r[1] = (short)f2bf(a[1]);
  r[2] = (short)f2bf(a[2]); r[3] = (short)f2bf(a[3]);
  r[4] = (short)f2bf(b[0]); r[5] = (short)f2bf(b[1]);
  r[6] = (short)f2bf(b[2]); r[7] = (short)f2bf(b[3]);
  return r;
}

// async global->LDS, 16B/lane; HW scatters lane i to ldsbase + i*16
__device__ __forceinline__ void gl2lds16(const u16* g, u16* l) {
  __builtin_amdgcn_global_load_lds(
      (const __attribute__((address_space(1))) uint32_t*)g,
      (__attribute__((address_space(3))) uint32_t*)l, 16, 0, 0);
}

// ---------------------------------------------------------------------------
// fp32 -> bf16 conversion: 4 weights (1M elem) + 3 activations (4.19M elem).
// ---------------------------------------------------------------------------
struct Cvt7 { const float* s[7]; u16* d[7]; int n[7]; };

__global__ __launch_bounds__(256) void cvt7(Cvt7 p) {
  const int z = blockIdx.y;
  const int idx = blockIdx.x * 256 + threadIdx.x;
  if (idx * 8 < p.n[z])
    *(s16x8*)(p.d[z] + (size_t)idx * 8) = ld8f(p.s[z] + (size_t)idx * 8);
}

// ---------------------------------------------------------------------------
// GEMM: C[M,N] = (A[M,K] @ W[N,K]^T + bias[N]) * scl; A,W bf16, bias fp32.
// Template: BM x BN tile (BK=64 fixed), 4 waves as 2x2 of (BM/2 x BN/2).
// OUT_F32: fp32 C (O projection). VT: z==2 writes transposed bf16 to p.vt.
// XCD swizzle: lid = (w&7)*(nwg/8) + w/8 groups contiguous bm-rows per XCD.
// ---------------------------------------------------------------------------
struct GemmBatch {
  const u16* A[3]; const u16* W[3]; const float* Bv[3]; void* C[3];
  u16* vt;       // VT destination: Vt[(b*16+h)*64+dh][s], row stride S_LEN
  float scl[3];  // epilogue scale (fp32, applied before f2bf round)
};

template <int BM, int BN, bool OUT_F32, bool VT>
__global__ __launch_bounds__(256) void gemm_bt(GemmBatch p, int M, int N, int K) {
  static_assert(!VT || BM == 128, "VT epilogue assumes BM=128 (batch arith)");
  constexpr int MI = BM / 32, NJ = BN / 32;   // fragment repeats per wave
  constexpr int TS = BM + 8;                  // VT transpose stride (u16), 16B-aligned
  constexpr int AB = BM * 64 + BN * 64;
  constexpr int TB = VT ? BN * TS : 0;
  constexpr int SM = AB > TB ? AB : TB;
  __shared__ u16 smem[SM];
  u16* const As = smem;
  u16* const Ws = smem + BM * 64;

  const int z = blockIdx.z;
  const u16* __restrict__ A      = p.A[z];
  const u16* __restrict__ W      = p.W[z];
  const float* __restrict__ bias = p.Bv[z];
  const float scl = p.scl[z];

  const int tid = threadIdx.x;
  const int wave = tid >> 6, lane = tid & 63;
  const int quad = lane >> 4, l16 = lane & 15;

  // XCD-aware bijective swizzle (nwg divisible by 8 for all our grids)
  const int nwg = gridDim.x * gridDim.y;
  const int w = blockIdx.x + gridDim.x * blockIdx.y;
  const int lid = (w & 7) * (nwg >> 3) + (w >> 3);
  const int bm = (lid / gridDim.x) * BM, bn = (lid % gridDim.x) * BN;

  const int wr = (wave >> 1) * (BM / 2), wc = (wave & 1) * (BN / 2);
  const int sr8 = lane >> 3;
  const int slc = (lane & 7) ^ sr8;           // logical k-chunk to fetch
  const int srow = wave * 8 + sr8;            // row within 32-row stripe

  f32x4 acc[MI][NJ];
#pragma unroll
  for (int i = 0; i < MI; i++)
#pragma unroll
    for (int j = 0; j < NJ; j++) acc[i][j] = {0.f, 0.f, 0.f, 0.f};

  const u16* Ab = A + (size_t)bm * K;
  const u16* Wb = W + (size_t)bn * K;

  for (int kt = 0; kt < K; kt += 64) {
    __syncthreads();  // previous iteration's LDS reads complete
#pragma unroll
    for (int i = 0; i < MI; i++)
      gl2lds16(Ab + (size_t)(i * 32 + srow) * K + kt + slc * 8,
               &As[(i * 32 + wave * 8) * 64]);
#pragma unroll
    for (int i = 0; i < NJ; i++)
      gl2lds16(Wb + (size_t)(i * 32 + srow) * K + kt + slc * 8,
               &Ws[(i * 32 + wave * 8) * 64]);
    __syncthreads();  // drains vmcnt (async loads) + LDS visible

#pragma unroll
    for (int ks = 0; ks < 2; ks++) {
      const int ch = ks * 4 + quad;  // logical chunk of this fragment
      s16x8 a[MI], b[NJ];
#pragma unroll
      for (int t = 0; t < MI; t++)
        a[t] = *(const s16x8*)&As[(wr + t * 16 + l16) * 64 + ((ch ^ (l16 & 7)) << 3)];
#pragma unroll
      for (int t = 0; t < NJ; t++)
        b[t] = *(const s16x8*)&Ws[(wc + t * 16 + l16) * 64 + ((ch ^ (l16 & 7)) << 3)];
#pragma unroll
      for (int i = 0; i < MI; i++)
#pragma unroll
        for (int j = 0; j < NJ; j++)
          acc[i][j] = __builtin_amdgcn_mfma_f32_16x16x32_bf16(a[i], b[j], acc[i][j], 0, 0, 0);
    }
  }

  if (VT && z == 2) {
    // ---- fused V transpose: acc -> LDS [col][row] -> Vt[d-row][s] ----
    __syncthreads();               // all waves done reading As/Ws
    u16* const T = smem;           // [BN][TS]
#pragma unroll
    for (int j = 0; j < NJ; j++) {
      const int c = wc + j * 16 + l16;
      const float bv = bias[bn + c];
#pragma unroll
      for (int i = 0; i < MI; i++) {
        const int r0 = wr + i * 16 + quad * 4;
        u16x4 t4;
#pragma unroll
        for (int r = 0; r < 4; r++) t4[r] = f2bf((acc[i][j][r] + bv) * scl);
        *(u16x4*)&T[c * TS + r0] = t4;
      }
    }
    __syncthreads();
    // copy out: SEG threads per column, run = BM/SEG contiguous s per thread
    constexpr int SEG = 256 / BN;            // 2 (BN=128) or 4 (BN=64)
    constexpr int RUN = BM / SEG;            // 64 or 32
    const int c = tid / SEG, seg = tid % SEG;
    const int b_ = bm >> 11;                 // batch (2048 rows each, 128 | 2048)
    const int sb = (bm & 2047) + seg * RUN;  // s within batch
    u16* dst = p.vt + (size_t)(b_ * 1024 + bn + c) * S_LEN + sb;
    const u16* srcT = &T[c * TS + seg * RUN];
#pragma unroll
    for (int k = 0; k < RUN / 8; k++)
      *(s16x8*)(dst + k * 8) = *(const s16x8*)(srcT + k * 8);
  } else {
    // epilogue: C/D layout row = quad*4 + reg, col = lane&15
#pragma unroll
    for (int j = 0; j < NJ; j++) {
      const int col = bn + wc + j * 16 + l16;
      const float bv = bias[col];
#pragma unroll
      for (int i = 0; i < MI; i++) {
        const int row0 = bm + wr + i * 16 + quad * 4;
#pragma unroll
        for (int r = 0; r < 4; r++) {
          const float val = (acc[i][j][r] + bv) * scl;
          if (OUT_F32)
            ((float*)p.C[z])[(size_t)(row0 + r) * N + col] = val;
          else
            ((u16*)p.C[z])[(size_t)(row0 + r) * N + col] = f2bf(val);
        }
      }
    }
  }
}

// ---------------------------------------------------------------------------
// Flash attention (R13 structure + R17 swizzle): 512 threads = 8 waves =
// 4 q-tiles(32 rows) x 2 kv-halves. Grid (16,32). R18: Q fragments loaded
// directly from global (Qs staging deleted); LDS 34KB (Ks 16 + Vs 16 + 2 merge).
// ---------------------------------------------------------------------------
__global__ __launch_bounds__(512, 4) void attn_kernel(const u16* __restrict__ Qp,
                                                      const u16* __restrict__ Kp,
                                                      const u16* __restrict__ Vt,
                                                      u16* __restrict__ AO) {
  __shared__ u16 smem[17408];    // 34 KB (16 Ks + 16 Vs; merge overlays 34)
  u16* const Ks = smem;          // [kv:128][d:64] 16 KB, 8-chunk XOR swizzle
  u16* const Vs = smem + 8192;   // [d:64][kv:128] 16 KB, 16-chunk XOR swizzle

  const int tid = threadIdx.x;
  const int wave = tid >> 6, lane = tid & 63;
  const int quad = lane >> 4, l16 = lane & 15;

  // XCD swizzle: w = x + 16y, nwg=512 -> 64 lids/XCD -> bh in [4j,4j+4)
  const int w = blockIdx.x + gridDim.x * blockIdx.y;
  const int lid = (w & 7) * 64 + (w >> 3);
  const int bh = lid >> 4, b = bh >> 4, h = bh & 15;
  const int s0 = (lid & 15) * 128;

  const int qw = wave & 3;        // q-tile index (32 rows each)
  const int kvh = wave >> 2;      // kv half (64 kv rows each)

  const int sr = tid >> 3, sc8 = tid & 7;
  const int sxor = (sc8 ^ (sr & 7)) << 3;
  const int vr = tid >> 4, vc = tid & 15;
  const int vxor = (vc ^ (vr & 15)) << 3;

  // ---- Q fragments: direct global load (same values staging delivered) ----
  s16x8 aq[2][2];  // [ks][rt]
#pragma unroll
  for (int ks = 0; ks < 2; ks++)
#pragma unroll
    for (int rt = 0; rt < 2; rt++) {
      const int row = qw * 32 + rt * 16 + l16;
      const int ch = ks * 4 + quad;
      aq[ks][rt] = *(const s16x8*)(Qp + (size_t)(b * S_LEN + s0 + row) * DMODEL + h * 64 + ch * 8);
    }

  // ---- K/V register prefetch for kt=0 (cooperative staging) ----
  s16x8 kv[2], vv[2];
#pragma unroll
  for (int i = 0; i < 2; i++)
    kv[i] = *(const s16x8*)(Kp + (size_t)(b * S_LEN + i * 64 + sr) * DMODEL + h * 64 + sc8 * 8);
#pragma unroll
  for (int i = 0; i < 2; i++)
    vv[i] = *(const s16x8*)(Vt + (size_t)(bh * 64 + i * 32 + vr) * S_LEN + vc * 8);

  f32x4 o[2][4];
  float l_r[2] = {0.f, 0.f};
#pragma unroll
  for (int rt = 0; rt < 2; rt++)
#pragma unroll
    for (int dt = 0; dt < 4; dt++) o[rt][dt] = {0.f, 0.f, 0.f, 0.f};

  const f32x4 zf = {0.f, 0.f, 0.f, 0.f};

  for (int kt = 0; kt < S_LEN; kt += 128) {
    __syncthreads();
#pragma unroll
    for (int i = 0; i < 2; i++)
      *(s16x8*)&Ks[(i * 64 + sr) * 64 + sxor] = kv[i];
#pragma unroll
    for (int i = 0; i < 2; i++)
      *(s16x8*)&Vs[(i * 32 + vr) * 128 + vxor] = vv[i];
    __syncthreads();

    if (kt + 128 < S_LEN) {
      const int k2 = kt + 128;
#pragma unroll
      for (int i = 0; i < 2; i++)
        kv[i] = *(const s16x8*)(Kp + (size_t)(b * S_LEN + k2 + i * 64 + sr) * DMODEL + h * 64 + sc8 * 8);
#pragma unroll
      for (int i = 0; i < 2; i++)
        vv[i] = *(const s16x8*)(Vt + (size_t)(bh * 64 + i * 32 + vr) * S_LEN + k2 + vc * 8);
    }

    // this wave's kv half: rows kvh*64 .. kvh*64+63 (4 subtiles of 16)
#pragma unroll
    for (int kvt = 0; kvt < 4; kvt++) {
      const int krow = kvh * 64 + kvt * 16 + l16;   // krow&7 == l16&7
      s16x8 ak0 = *(const s16x8*)&Ks[krow * 64 + (((0 + quad) ^ (l16 & 7)) << 3)];
      s16x8 ak1 = *(const s16x8*)&Ks[krow * 64 + (((4 + quad) ^ (l16 & 7)) << 3)];

      s16x4 pf[2];
#pragma unroll
      for (int rt = 0; rt < 2; rt++) {
        f32x4 sA;
        sA = __builtin_amdgcn_mfma_f32_16x16x32_bf16(ak0, aq[0][rt], zf, 0, 0, 0);
        sA = __builtin_amdgcn_mfma_f32_16x16x32_bf16(ak1, aq[1][rt], sA, 0, 0, 0);

        union { float f; uint32_t u; } e0, e1, e2, e3;
        e0.f = __builtin_amdgcn_exp2f(sA[0]);
        e1.f = __builtin_amdgcn_exp2f(sA[1]);
        e2.f = __builtin_amdgcn_exp2f(sA[2]);
        e3.f = __builtin_amdgcn_exp2f(sA[3]);
        l_r[rt] += (((e0.f + e1.f) + e2.f) + e3.f);

        union { uint32_t u[2]; s16x4 v; } pk;
        pk.u[0] = __builtin_amdgcn_perm(e1.u + 0x8000u, e0.u + 0x8000u, 0x07060302u);
        pk.u[1] = __builtin_amdgcn_perm(e3.u + 0x8000u, e2.u + 0x8000u, 0x07060302u);
        pf[rt] = pk.v;
      }

      const int ch = kvh * 8 + kvt * 2 + (quad >> 1);
#pragma unroll
      for (int dt = 0; dt < 4; dt++) {
        const int row = dt * 16 + l16;
        s16x4 bv = *(const s16x4*)&Vs[row * 128 + ((ch ^ l16) << 3) + (quad & 1) * 4];
        o[0][dt] = __builtin_amdgcn_mfma_f32_16x16x16bf16_1k(pf[0], bv, o[0][dt], 0, 0, 0);
        o[1][dt] = __builtin_amdgcn_mfma_f32_16x16x16bf16_1k(pf[1], bv, o[1][dt], 0, 0, 0);
      }
    }
  }

  // intra-wave l reduction (sum over quads -> value depends on l16 only)
#pragma unroll
  for (int rt = 0; rt < 2; rt++) {
    l_r[rt] += __shfl_xor(l_r[rt], 16);
    l_r[rt] += __shfl_xor(l_r[rt], 32);
  }

  // ---- cross-half merge: waves 4..7 dump O/l into reused staging LDS ----
  __syncthreads();  // all LDS reads of last ktile complete
  f32x4* const mrgO = (f32x4*)smem;            // [rt*4+dt][w*64+lane], 32 KB
  float* const mrgL = (float*)smem + 8192;     // [rt][w*64+lane], 2 KB @ 32 KB
  if (wave >= 4) {
    const int w4 = wave - 4;
#pragma unroll
    for (int rt = 0; rt < 2; rt++) {
#pragma unroll
      for (int dt = 0; dt < 4; dt++)
        mrgO[(rt * 4 + dt) * 256 + w4 * 64 + lane] = o[rt][dt];
      mrgL[rt * 256 + w4 * 64 + lane] = l_r[rt];
    }
  }
  __syncthreads();
  if (wave < 4) {
#pragma unroll
    for (int rt = 0; rt < 2; rt++) {
#pragma unroll
      for (int dt = 0; dt < 4; dt++) {
        f32x4 ov = mrgO[(rt * 4 + dt) * 256 + wave * 64 + lane];
        o[rt][dt] += ov;
      }
      l_r[rt] += mrgL[rt * 256 + wave * 64 + lane];
    }
#pragma unroll
    for (int rt = 0; rt < 2; rt++) {
#pragma unroll
      for (int r = 0; r < 4; r++) {
        const float linv = 1.f / __shfl(l_r[rt], quad * 4 + r);
        const int row = s0 + qw * 32 + rt * 16 + quad * 4 + r;
#pragma unroll
        for (int dt = 0; dt < 4; dt++)
          AO[(size_t)(b * S_LEN + row) * DMODEL + h * 64 + dt * 16 + l16] =
              f2bf(o[rt][dt][r] * linv);
      }
    }
  }
}

// ---------------------------------------------------------------------------
extern "C" void kernel_launch(void* const* d_in, const int* in_sizes, int n_in,
                              void* d_out, int out_size, void* d_ws, size_t ws_size,
                              hipStream_t stream) {
  const float* query = (const float*)d_in[0];
  const float* key_  = (const float*)d_in[1];
  const float* value = (const float*)d_in[2];
  const float* W_q = (const float*)d_in[3];
  const float* b_q = (const float*)d_in[4];
  const float* W_k = (const float*)d_in[5];
  const float* b_k = (const float*)d_in[6];
  const float* W_v = (const float*)d_in[7];
  const float* b_v = (const float*)d_in[8];
  const float* W_o = (const float*)d_in[9];
  const float* b_o = (const float*)d_in[10];
  float* out = (float*)d_out;

  const int M = 2 * S_LEN;  // 4096
  const int N = DMODEL, K = DMODEL;
  const size_t WSZ = (size_t)DMODEL * DMODEL;   // 1,048,576
  const size_t SZ  = (size_t)M * DMODEL;        // 4,194,304

  u16* Wqb = (u16*)d_ws;         // 4 bf16 weights
  u16* Wkb = Wqb + WSZ;
  u16* Wvb = Wkb + WSZ;
  u16* Wob = Wvb + WSZ;
  u16* Qa  = Wob + WSZ;          // bf16 inputs (dead after QKV GEMM)
  u16* Ka  = Qa + SZ;
  u16* Va  = Ka + SZ;
  u16* Qp  = Va + SZ;            // projections
  u16* Kp  = Qp + SZ;
  u16* Vt  = Kp + SZ;            // [B,H,Dh,S] -- written directly by V-GEMM (VT path)
  u16* AO  = Qp;                 // aliases Qp (per-block disjoint read->write)

  Cvt7 cw;
  cw.s[0] = W_q;   cw.d[0] = Wqb; cw.n[0] = (int)WSZ;
  cw.s[1] = W_k;   cw.d[1] = Wkb; cw.n[1] = (int)WSZ;
  cw.s[2] = W_v;   cw.d[2] = Wvb; cw.n[2] = (int)WSZ;
  cw.s[3] = W_o;   cw.d[3] = Wob; cw.n[3] = (int)WSZ;
  cw.s[4] = query; cw.d[4] = Qa;  cw.n[4] = (int)SZ;
  cw.s[5] = key_;  cw.d[5] = Ka;  cw.n[5] = (int)SZ;
  cw.s[6] = value; cw.d[6] = Va;  cw.n[6] = (int)SZ;
  cvt7<<<dim3((int)(SZ / 2048), 7), 256, 0, stream>>>(cw);

  GemmBatch p1;
  p1.A[0] = Qa; p1.W[0] = Wqb; p1.Bv[0] = b_q; p1.C[0] = Qp;
  p1.A[1] = Ka; p1.W[1] = Wkb; p1.Bv[1] = b_k; p1.C[1] = Kp;
  p1.A[2] = Va; p1.W[2] = Wvb; p1.Bv[2] = b_v; p1.C[2] = Vt;  // unused (VT path)
  p1.vt = Vt;
  p1.scl[0] = 0.03125f * LOG2E;  // d_model^-0.5 * log2(e) folded into Q (fp32)
  p1.scl[1] = 1.0f;
  p1.scl[2] = 1.0f;
  gemm_bt<128, 64, false, true><<<dim3(N / 64, M / 128, 3), 256, 0, stream>>>(p1, M, N, K);

  attn_kernel<<<dim3(S_LEN / 128, 32), 512, 0, stream>>>(Qp, Kp, Vt, AO);

  GemmBatch p2;
  p2.A[0] = AO; p2.W[0] = Wob; p2.Bv[0] = b_o; p2.C[0] = out;
  p2.A[1] = AO; p2.W[1] = Wob; p2.Bv[1] = b_o; p2.C[1] = out;
  p2.A[2] = AO; p2.W[2] = Wob; p2.Bv[2] = b_o; p2.C[2] = out;
  p2.vt = nullptr;
  p2.scl[0] = 1.0f; p2.scl[1] = 1.0f; p2.scl[2] = 1.0f;
  gemm_bt<64, 64, true, false><<<dim3(N / 64, M / 64, 1), 256, 0, stream>>>(p2, M, N, K);
}